// Round 2
// baseline (450.970 us; speedup 1.0000x reference)
//
#include <hip/hip_runtime.h>

// DynamicVoxelizer: B=8, N=1e6, C=4 fp32 points -> 5 concatenated outputs
// (points_out[B,N,4], voxel_coords[B,N,3], point_idxes[B,N],
//  point_offsets[B,N,3], valid[B,N]) written as float values into d_out.
//
// R1/R2: LDS-stage the 3-wide/scalar outputs so every global store is a
//        lane-contiguous dwordx4 (12B/lane struct stores capped write BW).
// R3: NT-store removal — NEUTRAL. Write path is not the limiter.
// R4: restructure for issue efficiency: each WAVE independently owns 256
//     consecutive points (4/lane). 4 loads in flight per thread (was 1),
//     __syncthreads eliminated (per-wave LDS slices + in-wave lgkmcnt
//     ordering), phase-2 is a 12-slot full-wave store burst, each slot a
//     contiguous 1KB write to one region. The 6.3 TB/s fill proves BW needs
//     store-issue duty cycle, not occupancy; the old kernel's mid-block
//     barrier + 1-load MLP held it to ~2.6 TB/s.

#define NPTS 1000000  // N (points per batch) — fixed by the problem
#define BLK 128       // 2 waves per block
#define WPT 256       // points per wave (4 per lane); block covers 512 pts

typedef float f4 __attribute__((ext_vector_type(4)));

__global__ __launch_bounds__(BLK) void voxelize_kernel(
    const f4* __restrict__ pts, float* __restrict__ out, int total) {
  // Per-WAVE LDS slices — no cross-wave sharing, no __syncthreads.
  __shared__ __align__(16) float s_vox [2][WPT * 3];
  __shared__ __align__(16) float s_poff[2][WPT * 3];
  __shared__ __align__(16) float s_misc[2][WPT * 2];  // idx[256] | val[256]

  const int lane  = threadIdx.x & 63;
  const int wave  = threadIdx.x >> 6;
  const int pbase = blockIdx.x * ((BLK / 64) * WPT) + wave * WPT;

  // Issue all 4 loads up front — 4x memory-level parallelism per thread.
  f4 p[4];
#pragma unroll
  for (int k = 0; k < 4; ++k)
    p[k] = __builtin_nontemporal_load(&pts[pbase + k * 64 + lane]);

  float* sv = s_vox[wave];
  float* so = s_poff[wave];
  float* sm = s_misc[wave];

#pragma unroll
  for (int k = 0; k < 4; ++k) {
    const int i = pbase + k * 64 + lane;
    f4 q = p[k];
    bool has_nan = (q.x != q.x) | (q.y != q.y) | (q.z != q.z) | (q.w != q.w);

    // cf = floor((xyz - pmin) / vs) — IEEE sub + correctly-rounded div to
    // match numpy op-for-op (a 1-voxel flip breaks point_offsets tolerance).
    float fx = floorf((q.x - (-51.2f)) / 0.1f);
    float fy = floorf((q.y - (-51.2f)) / 0.1f);
    float fz = floorf((q.z - (-5.0f))  / 0.2f);
    int cx = (int)fx, cy = (int)fy, cz = (int)fz;

    bool in_range = (cx >= 0) & (cx < 1024) &
                    (cy >= 0) & (cy < 1024) &
                    (cz >= 0) & (cz < 40);
    bool valid = (!has_nan) && in_range;

    float ox = q.x - (fx * 0.1f + (-51.2f) + 0.05f);
    float oy = q.y - (fy * 0.1f + (-51.2f) + 0.05f);
    float oz = q.z - (fz * 0.2f + (-5.0f)  + 0.1f);

    // points_out: 16B/lane contiguous — store direct, as data arrives.
    f4 po = valid ? q : (f4){0.0f, 0.0f, 0.0f, 0.0f};
    ((f4*)out)[i] = po;

    // Stage into this wave's LDS slice (stride-3 dword = 2-way = free).
    const int s = k * 64 + lane;
    sv[s * 3 + 0] = valid ? (float)cz : -1.0f;  // reversed (z,y,x)
    sv[s * 3 + 1] = valid ? (float)cy : -1.0f;
    sv[s * 3 + 2] = valid ? (float)cx : -1.0f;
    so[s * 3 + 0] = valid ? ox : 0.0f;
    so[s * 3 + 1] = valid ? oy : 0.0f;
    so[s * 3 + 2] = valid ? oz : 0.0f;
    sm[s]       = valid ? (float)(i % NPTS) : -1.0f;  // arange(N) per batch
    sm[WPT + s] = valid ? 1.0f : 0.0f;
  }

  // In-wave ordering only: compiler emits lgkmcnt before the dependent
  // ds_reads; wave_barrier pins scheduling at zero HW cost. No s_barrier.
  __builtin_amdgcn_wave_barrier();

  const long long t = total;
  // Region bases (floats). pbase is a multiple of 256 -> pbase*3/4 integral;
  // all f4 casts 16B-aligned for total % 512 == 0.
  f4* gvox  = (f4*)(out + 4  * t) + (long long)pbase * 3 / 4;  // 192 f4/wave
  f4* gpoff = (f4*)(out + 8  * t) + (long long)pbase * 3 / 4;  // 192 f4/wave
  f4* gidx  = (f4*)(out + 7  * t) + pbase / 4;                 // 64 f4/wave
  f4* gval  = (f4*)(out + 11 * t) + pbase / 4;                 // 64 f4/wave

  const f4* v4 = (const f4*)sv;
  const f4* o4 = (const f4*)so;
  const f4* m4 = (const f4*)sm;

  // 8-slot store burst: every slot is a full-wave, 1KB-contiguous write to a
  // single region. Fire-and-forget; wave retires after issue.
#pragma unroll
  for (int j = 0; j < 3; ++j) gvox[j * 64 + lane] = v4[j * 64 + lane];
#pragma unroll
  for (int j = 0; j < 3; ++j) gpoff[j * 64 + lane] = o4[j * 64 + lane];
  gidx[lane] = m4[lane];
  gval[lane] = m4[64 + lane];
}

// Scalar tail path for total % 512 != 0 (unused at B*N = 8e6, kept for safety).
__global__ __launch_bounds__(64) void voxelize_tail(
    const float* __restrict__ ptsf, float* __restrict__ out, int total, int start) {
  int i = start + blockIdx.x * blockDim.x + threadIdx.x;
  if (i >= total) return;
  float px = ptsf[i * 4 + 0], py = ptsf[i * 4 + 1];
  float pz = ptsf[i * 4 + 2], pw = ptsf[i * 4 + 3];
  bool has_nan = (px != px) | (py != py) | (pz != pz) | (pw != pw);
  float fx = floorf((px - (-51.2f)) / 0.1f);
  float fy = floorf((py - (-51.2f)) / 0.1f);
  float fz = floorf((pz - (-5.0f))  / 0.2f);
  int cx = (int)fx, cy = (int)fy, cz = (int)fz;
  bool in_range = (cx >= 0) & (cx < 1024) & (cy >= 0) & (cy < 1024) &
                  (cz >= 0) & (cz < 40);
  bool valid = (!has_nan) && in_range;
  float ox = px - (fx * 0.1f + (-51.2f) + 0.05f);
  float oy = py - (fy * 0.1f + (-51.2f) + 0.05f);
  float oz = pz - (fz * 0.2f + (-5.0f)  + 0.1f);
  long long t = total;
  out[i * 4 + 0] = valid ? px : 0.0f;
  out[i * 4 + 1] = valid ? py : 0.0f;
  out[i * 4 + 2] = valid ? pz : 0.0f;
  out[i * 4 + 3] = valid ? pw : 0.0f;
  float* vox  = out + 4 * t  + (long long)i * 3;
  float* poff = out + 8 * t  + (long long)i * 3;
  if (valid) {
    vox[0] = (float)cz; vox[1] = (float)cy; vox[2] = (float)cx;
    poff[0] = ox; poff[1] = oy; poff[2] = oz;
    out[7 * t + i]  = (float)(i % NPTS);
    out[11 * t + i] = 1.0f;
  } else {
    vox[0] = -1.0f; vox[1] = -1.0f; vox[2] = -1.0f;
    poff[0] = 0.0f; poff[1] = 0.0f; poff[2] = 0.0f;
    out[7 * t + i]  = -1.0f;
    out[11 * t + i] = 0.0f;
  }
}

extern "C" void kernel_launch(void* const* d_in, const int* in_sizes, int n_in,
                              void* d_out, int out_size, void* d_ws, size_t ws_size,
                              hipStream_t stream) {
  (void)n_in; (void)d_ws; (void)ws_size; (void)out_size;
  const f4* pts = (const f4*)d_in[0];
  float* out = (float*)d_out;
  int total = in_sizes[0] / 4;  // B*N = 8,000,000
  const int ppb = (BLK / 64) * WPT;  // 512 points per block
  int full_blocks = total / ppb;     // 15625 exact at 8e6
  if (full_blocks > 0)
    voxelize_kernel<<<full_blocks, BLK, 0, stream>>>(pts, out, total);
  int rem = total - full_blocks * ppb;
  if (rem > 0)
    voxelize_tail<<<(rem + 63) / 64, 64, 0, stream>>>((const float*)d_in[0], out,
                                                      total, full_blocks * ppb);
}